// Round 13
// baseline (286.144 us; speedup 1.0000x reference)
//
#include <hip/hip_runtime.h>
#include <hip/hip_fp16.h>

// DSMoE: x(8,2048,512) f32, gate_w(512,4), w1(4,512,2048), w2(4,2048,512)
// out = [ (8,2048,512) f32 ; router_sparse (16384,4) f32 ]
// R13: counted-vmcnt pipeline at preserved occupancy. 256x128 tiles, 512thr,
//      A 3-buf (lead-2) + B 2-buf (lead-1), 64KB LDS -> 2 blk/CU, vmcnt(2)
//      + single barrier per K-tile (R12 drained vmcnt(0) every step = critical
//      path per m252). Expert regions 256-aligned (CAP 33792).

#define NTOK  16384
#define CDIM  512
#define FF    2048
#define NEXP  4
#define CAP   33792    // 32768 + 4*256 (264 blocks of 128 / 132 of 256)
#define NBLK  264
#define BM    128      // host chunk unit (gemm tiles are 256 rows = 2 units)
#define NT1   16       // gemm1 K-tiles (512/32)
#define NT2   64       // gemm2 K-tiles (2048/32)
#define CPAD  32

typedef _Float16 f16;
typedef __attribute__((ext_vector_type(8))) _Float16 f16x8;
typedef __attribute__((ext_vector_type(4))) _Float16 f16x4;
typedef __attribute__((ext_vector_type(4))) float f32x4;

__device__ __forceinline__ void gload16(const void* g, void* l) {
  __builtin_amdgcn_global_load_lds(
      (const __attribute__((address_space(1))) unsigned int*)g,
      (__attribute__((address_space(3))) unsigned int*)l, 16, 0, 0);
}

__device__ __forceinline__ float gelu_fast(float v) {
  float az = fabsf(v) * 0.7071067811865476f;
  float t = __builtin_amdgcn_rcpf(fmaf(0.3275911f, az, 1.0f));
  float p = fmaf(fmaf(fmaf(fmaf(1.061405429f, t, -1.453152027f), t,
                           1.421413741f), t, -0.284496736f), t, 0.254829592f) * t;
  float e = __builtin_amdgcn_exp2f(az * az * -1.4426950408889634f);
  float erfa = fmaf(-p, e, 1.0f);
  float u = copysignf(erfa, v);
  return 0.5f * v * (1.0f + u);
}

__device__ __forceinline__ int xcd_swz(int bid, int nwg) {
  int q = nwg >> 3, r = nwg & 7;
  int x = bid & 7, o = bid >> 3;
  return (x < r ? x * (q + 1) : r * (q + 1) + (x - r) * q) + o;
}

// ---------------- small utility kernels ----------------

__global__ __launch_bounds__(256) void k_init(int* list, int* cnt) {
  int i = blockIdx.x * 256 + threadIdx.x;
  if (i < CAP) list[i] = -1;
  if (i < 4) cnt[i * CPAD] = 0;
}

__global__ __launch_bounds__(256) void k_cast_t(const float* __restrict__ in,
                                                f16* __restrict__ out, int R, int Cc) {
  __shared__ f16 T[64][72];
  int ez = blockIdx.z;
  const float* ine = in + (size_t)ez * R * Cc;
  f16* oute = out + (size_t)ez * R * Cc;
  int c0 = blockIdx.x * 64;
  int r0 = blockIdx.y * 64;
  int t = threadIdx.x;
  {
    int rr = t >> 2, cc = (t & 3) * 16;
    const float* src = ine + (size_t)(r0 + rr) * Cc + c0 + cc;
    union { f16 h[16]; uint4 u[2]; } pk;
#pragma unroll
    for (int j = 0; j < 16; j += 4) {
      float4 a = *(const float4*)(src + j);
      pk.h[j] = (f16)a.x; pk.h[j + 1] = (f16)a.y;
      pk.h[j + 2] = (f16)a.z; pk.h[j + 3] = (f16)a.w;
    }
    *(uint4*)&T[rr][cc] = pk.u[0];
    *(uint4*)&T[rr][cc + 8] = pk.u[1];
  }
  __syncthreads();
  {
    int oc = t >> 2, orr = (t & 3) * 16;
    union { f16 h[16]; uint4 u[2]; } pk;
#pragma unroll
    for (int j = 0; j < 16; ++j) pk.h[j] = T[orr + j][oc];
    f16* dst = oute + (size_t)(c0 + oc) * R + r0 + orr;
    *(uint4*)dst = pk.u[0];
    *(uint4*)(dst + 8) = pk.u[1];
  }
}

// ---------------- router (fp32 exact) + fused x->fp16 cast ----------------

__global__ __launch_bounds__(256) void k_router(const float* __restrict__ x,
                                                const float* __restrict__ gw,
                                                f16* __restrict__ xh,
                                                float* __restrict__ rout,
                                                float4* __restrict__ tokinfo,
                                                int* __restrict__ cnt) {
  __shared__ int lcnt[4];
  int tid = threadIdx.x;
  if (tid < 4) lcnt[tid] = 0;
  __syncthreads();
  int wv = tid >> 6, lane = tid & 63;
  const float4* g = ((const float4*)gw) + lane * 8;
  float4 gv[8];
#pragma unroll
  for (int j = 0; j < 8; ++j) gv[j] = g[j];

  int tok0 = blockIdx.x * 64 + wv * 16;
  for (int i = 0; i < 16; ++i) {
    int tok = tok0 + i;
    const float4* xr = (const float4*)(x + (size_t)tok * CDIM + lane * 8);
    float4 a0 = xr[0], a1 = xr[1];
    union { f16 h[8]; uint4 u; } pk;
    pk.h[0] = (f16)a0.x; pk.h[1] = (f16)a0.y; pk.h[2] = (f16)a0.z; pk.h[3] = (f16)a0.w;
    pk.h[4] = (f16)a1.x; pk.h[5] = (f16)a1.y; pk.h[6] = (f16)a1.z; pk.h[7] = (f16)a1.w;
    *(uint4*)(xh + (size_t)tok * CDIM + lane * 8) = pk.u;
    float xv[8] = {a0.x, a0.y, a0.z, a0.w, a1.x, a1.y, a1.z, a1.w};
    float l0 = 0, l1 = 0, l2 = 0, l3 = 0;
#pragma unroll
    for (int j = 0; j < 8; ++j) {
      float4 g4 = gv[j];
      l0 = fmaf(xv[j], g4.x, l0); l1 = fmaf(xv[j], g4.y, l1);
      l2 = fmaf(xv[j], g4.z, l2); l3 = fmaf(xv[j], g4.w, l3);
    }
#pragma unroll
    for (int off = 32; off; off >>= 1) {
      l0 += __shfl_xor(l0, off); l1 += __shfl_xor(l1, off);
      l2 += __shfl_xor(l2, off); l3 += __shfl_xor(l3, off);
    }
    if (lane == 0) {
      float lg[4] = {l0, l1, l2, l3};
      float m = fmaxf(fmaxf(lg[0], lg[1]), fmaxf(lg[2], lg[3]));
      float p[4], s = 0.f;
#pragma unroll
      for (int e = 0; e < 4; ++e) { p[e] = expf(lg[e] - m); s += p[e]; }
      int i0 = 0;
#pragma unroll
      for (int e = 1; e < 4; ++e) if (lg[e] > lg[i0]) i0 = e;
      int i1 = -1;
#pragma unroll
      for (int e = 0; e < 4; ++e)
        if (e != i0 && (i1 < 0 || lg[e] > lg[i1])) i1 = e;
      float p0 = p[i0] / s, p1 = p[i1] / s;
      float ss = fmaxf(p0 + p1, 1e-6f);
      float w0 = p0 / ss, w1v = p1 / ss;
      float r[4] = {0.f, 0.f, 0.f, 0.f};
      r[i0] = w0; r[i1] = w1v;
      *(float4*)(rout + tok * 4) = make_float4(r[0], r[1], r[2], r[3]);
      float4 ti;
      ti.x = __int_as_float(i0); ti.y = __int_as_float(i1); ti.z = w0; ti.w = w1v;
      tokinfo[tok] = ti;
      atomicAdd(&lcnt[i0], 1);
      atomicAdd(&lcnt[i1], 1);
    }
  }
  __syncthreads();
  if (tid < 4) atomicAdd(cnt + tid * CPAD, lcnt[tid]);
}

__global__ void k_bases(const int* __restrict__ cnt, int* __restrict__ base,
                        int* __restrict__ cursor) {
  if (threadIdx.x == 0 && blockIdx.x == 0) {
    int b = 0;
#pragma unroll
    for (int e = 0; e < 4; ++e) {
      base[e] = b; cursor[e * CPAD] = b;
      b += (cnt[e * CPAD] + 255) & ~255;   // 256-aligned regions
    }
    base[4] = b;
  }
}

__global__ __launch_bounds__(256) void k_assign(const float4* __restrict__ tokinfo,
                                                int* cursor, int* __restrict__ list,
                                                int2* __restrict__ tokslot) {
  __shared__ int lcnt[4], lbase[4];
  int tid = threadIdx.x;
  if (tid < 4) lcnt[tid] = 0;
  __syncthreads();
  int t0 = blockIdx.x * 1024 + tid * 4;
  float4 ti[4]; int lo0[4], lo1[4];
#pragma unroll
  for (int j = 0; j < 4; ++j) {
    ti[j] = tokinfo[t0 + j];
    lo0[j] = atomicAdd(&lcnt[__float_as_int(ti[j].x)], 1);
    lo1[j] = atomicAdd(&lcnt[__float_as_int(ti[j].y)], 1);
  }
  __syncthreads();
  if (tid < 4) lbase[tid] = atomicAdd(cursor + tid * CPAD, lcnt[tid]);
  __syncthreads();
#pragma unroll
  for (int j = 0; j < 4; ++j) {
    int s0 = lbase[__float_as_int(ti[j].x)] + lo0[j];
    list[s0] = t0 + j;
    int s1 = lbase[__float_as_int(ti[j].y)] + lo1[j];
    list[s1] = t0 + j;
    tokslot[t0 + j] = make_int2(s0, s1);
  }
}

// ---------------- pass 1: H[slot, :] = gelu(x[list] @ W1e) ----------------
// 256x128 tile, 512 thr (8 waves 4Mx2N), BK=32, A 3-buf + B 2-buf (64KB+slist),
// vmcnt(2) counted pipeline, one barrier per K-tile. 2 blocks/CU.

__global__ __launch_bounds__(512, 4) void k_gemm1(const f16* __restrict__ xh,
                                                  const f16* __restrict__ w1t, // [E][FF][C]
                                                  const int* __restrict__ list,
                                                  const int* __restrict__ base,
                                                  f16* __restrict__ H, int cb, int nwg) {
  __shared__ __align__(16) char smem[66560];   // A 3x16KB @0, B 2x8KB @49152, slist @65536
  int* slist = (int*)(smem + 65536);
  int tid = threadIdx.x;
  int wk = xcd_swz(blockIdx.x, nwg);
  int bx = wk >> 4, by = wk & 15;
  int m0 = cb * BM + bx * 256;
  int mloc = bx * 256;
  int h0 = by * 128;
  int e = 0;
#pragma unroll
  for (int i = 1; i < 4; ++i) if (m0 >= base[i]) e = i;
  if (tid < 256) {
    int v = list[m0 + tid];
    slist[tid] = v < 0 ? 0 : v;   // pads -> token 0: garbage rows, never read back
  }
  __syncthreads();

  int tokr[2];
#pragma unroll
  for (int l = 0; l < 2; ++l) tokr[l] = slist[l * 128 + (tid >> 2)];

  const f16* wB = w1t + (size_t)(e * FF + h0) * CDIM;
  int kbs = ((tid & 3) * 16) ^ (((tid >> 3) & 3) << 4);   // 64B-row involution

  f32x4 acc[4][4] = {};
  int lane = tid & 63, w = tid >> 6, wr = w >> 1, wc = w & 1;

  auto stageA = [&](int kt) {   // 2 gloads: 256 rows x 32 k
    char* s = smem + (kt % 3) * 16384;
#pragma unroll
    for (int l = 0; l < 2; ++l)
      gload16(xh + (size_t)tokr[l] * CDIM + kt * 32 + (kbs >> 1),
              s + l * 8192 + tid * 16);
  };
  auto stageB = [&](int kt) {   // 1 gload: 128 cols x 32 k
    char* s = smem + 49152 + (kt & 1) * 8192;
    gload16(wB + (size_t)(tid >> 2) * CDIM + kt * 32 + (kbs >> 1), s + tid * 16);
  };

  for (int kt = 0; kt < 2; ++kt) stageA(kt);
  stageB(0);
  asm volatile("s_waitcnt vmcnt(0)" ::: "memory");
  __builtin_amdgcn_s_barrier();

  for (int t = 0; t < NT1; ++t) {
    const char* sA = smem + (t % 3) * 16384;
    const char* sB = smem + 49152 + (t & 1) * 8192;
    int kb = (lane >> 4) * 16;
    f16x8 af[4], bf[4];
#pragma unroll
    for (int fc = 0; fc < 4; ++fc) {
      int col = wc * 64 + fc * 16 + (lane & 15);
      bf[fc] = *(const f16x8*)(sB + col * 64 + (kb ^ (((col >> 1) & 3) << 4)));
    }
#pragma unroll
    for (int fr = 0; fr < 4; ++fr) {
      int row = wr * 64 + fr * 16 + (lane & 15);
      af[fr] = *(const f16x8*)(sA + row * 64 + (kb ^ (((row >> 1) & 3) << 4)));
    }
    if (t + 1 < NT1) stageB(t + 1);
    if (t + 2 < NT1) {
      stageA(t + 2);
      asm volatile("s_waitcnt vmcnt(2)" ::: "memory");   // A(t+1),B(t+1) landed
    } else {
      asm volatile("s_waitcnt vmcnt(0)" ::: "memory");   // tail drain
    }
    asm volatile("s_waitcnt lgkmcnt(0)" ::: "memory");
    __builtin_amdgcn_sched_barrier(0);
    __builtin_amdgcn_s_setprio(1);
#pragma unroll
    for (int fr = 0; fr < 4; ++fr)
#pragma unroll
      for (int fc = 0; fc < 4; ++fc)
        acc[fr][fc] = __builtin_amdgcn_mfma_f32_16x16x32_f16(af[fr], bf[fc],
                                                             acc[fr][fc], 0, 0, 0);
    __builtin_amdgcn_s_setprio(0);
    __builtin_amdgcn_sched_barrier(0);
    __builtin_amdgcn_s_barrier();   // publish staged tiles; seal reads
  }

  // epilogue: gelu -> f16, LDS repack [256 rows][256B], coalesced 16B stores
#pragma unroll
  for (int fr = 0; fr < 4; ++fr)
#pragma unroll
    for (int fc = 0; fc < 4; ++fc)
#pragma unroll
      for (int i = 0; i < 4; ++i) {
        int row = wr * 64 + fr * 16 + (lane >> 4) * 4 + i;
        int col = wc * 64 + fc * 16 + (lane & 15);
        float v = gelu_fast(acc[fr][fc][i]);
        int off = (row * 256 + col * 2) ^ ((row & 7) << 4);
        *(f16*)(smem + off) = (f16)v;
      }
  __syncthreads();
#pragma unroll
  for (int j = 0; j < 8; ++j) {
    int row = j * 32 + (tid >> 4);
    int colb = ((tid & 15) * 16) ^ ((row & 7) << 4);
    uint4 v = *(const uint4*)(smem + row * 256 + colb);
    *(uint4*)((char*)H + ((size_t)(mloc + row) * FF + h0) * 2 + (tid & 15) * 16) = v;
  }
}

// ---------------- pass 2: Y[slot] = H[slot] @ W2e  (K = FF = 2048) ----------------
// Same pipeline; A = H rows direct. Grid (CB/2)*4 = 528 (~1.03 rounds @2/CU).

__global__ __launch_bounds__(512, 4) void k_gemm2(const f16* __restrict__ H,
                                                  const f16* __restrict__ w2t, // [E][C][FF]
                                                  const int* __restrict__ base,
                                                  f16* __restrict__ Y, int cb, int nwg) {
  __shared__ __align__(16) char smem[65536];   // A 3x16KB @0, B 2x8KB @49152
  int tid = threadIdx.x;
  int wk = xcd_swz(blockIdx.x, nwg);
  int bx = wk >> 2, by = wk & 3;
  int m0 = cb * BM + bx * 256;
  int mloc = bx * 256;
  int c0 = by * 128;
  int e = 0;
#pragma unroll
  for (int i = 1; i < 4; ++i) if (m0 >= base[i]) e = i;

  const f16* pA = H + (size_t)mloc * FF;
  const f16* wB = w2t + (size_t)(e * CDIM + c0) * FF;
  int kbs = ((tid & 3) * 16) ^ (((tid >> 3) & 3) << 4);

  f32x4 acc[4][4] = {};
  int lane = tid & 63, w = tid >> 6, wr = w >> 1, wc = w & 1;

  auto stageA = [&](int kt) {
    char* s = smem + (kt % 3) * 16384;
#pragma unroll
    for (int l = 0; l < 2; ++l) {
      int row = l * 128 + (tid >> 2);
      gload16(pA + (size_t)row * FF + kt * 32 + (kbs >> 1), s + l * 8192 + tid * 16);
    }
  };
  auto stageB = [&](int kt) {
    char* s = smem + 49152 + (kt & 1) * 8192;
    gload16(wB + (size_t)(tid >> 2) * FF + kt * 32 + (kbs >> 1), s + tid * 16);
  };

  for (int kt = 0; kt < 2; ++kt) stageA(kt);
  stageB(0);
  asm volatile("s_waitcnt vmcnt(0)" ::: "memory");
  __builtin_amdgcn_s_barrier();

  for (int t = 0; t < NT2; ++t) {
    const char* sA = smem + (t % 3) * 16384;
    const char* sB = smem + 49152 + (t & 1) * 8192;
    int kb = (lane >> 4) * 16;
    f16x8 af[4], bf[4];
#pragma unroll
    for (int fc = 0; fc < 4; ++fc) {
      int col = wc * 64 + fc * 16 + (lane & 15);
      bf[fc] = *(const f16x8*)(sB + col * 64 + (kb ^ (((col >> 1) & 3) << 4)));
    }
#pragma unroll
    for (int fr = 0; fr < 4; ++fr) {
      int row = wr * 64 + fr * 16 + (lane & 15);
      af[fr] = *(const f16x8*)(sA + row * 64 + (kb ^ (((row >> 1) & 3) << 4)));
    }
    if (t + 1 < NT2) stageB(t + 1);
    if (t + 2 < NT2) {
      stageA(t + 2);
      asm volatile("s_waitcnt vmcnt(2)" ::: "memory");
    } else {
      asm volatile("s_waitcnt vmcnt(0)" ::: "memory");
    }
    asm volatile("s_waitcnt lgkmcnt(0)" ::: "memory");
    __builtin_amdgcn_sched_barrier(0);
    __builtin_amdgcn_s_setprio(1);
#pragma unroll
    for (int fr = 0; fr < 4; ++fr)
#pragma unroll
      for (int fc = 0; fc < 4; ++fc)
        acc[fr][fc] = __builtin_amdgcn_mfma_f32_16x16x32_f16(af[fr], bf[fc],
                                                             acc[fr][fc], 0, 0, 0);
    __builtin_amdgcn_s_setprio(0);
    __builtin_amdgcn_sched_barrier(0);
    __builtin_amdgcn_s_barrier();
  }

  // epilogue: f16 -> LDS repack [256][256B] -> coalesced 16B stores
#pragma unroll
  for (int fr = 0; fr < 4; ++fr)
#pragma unroll
    for (int fc = 0; fc < 4; ++fc)
#pragma unroll
      for (int i = 0; i < 4; ++i) {
        int row = wr * 64 + fr * 16 + (lane >> 4) * 4 + i;
        int col = wc * 64 + fc * 16 + (lane & 15);
        int off = (row * 256 + col * 2) ^ ((row & 7) << 4);
        *(f16*)(smem + off) = (f16)acc[fr][fc][i];
      }
  __syncthreads();
#pragma unroll
  for (int j = 0; j < 8; ++j) {
    int row = j * 32 + (tid >> 4);
    int colb = ((tid & 15) * 16) ^ ((row & 7) << 4);
    uint4 v = *(const uint4*)(smem + row * 256 + colb);
    *(uint4*)((char*)Y + ((size_t)(m0 + row) * CDIM + c0) * 2 + (tid & 15) * 16) = v;
  }
}

// ---------------- combine: out[tok] = w0*Y[s0] + w1*Y[s1] ----------------

__global__ __launch_bounds__(256) void k_combine(const f16* __restrict__ Y,
                                                 const float4* __restrict__ tokinfo,
                                                 const int2* __restrict__ tokslot,
                                                 float* __restrict__ out) {
  int gid = blockIdx.x * 256 + threadIdx.x;
  int tok = gid >> 7;
  int cc = (gid & 127) * 4;
  int2 sl = tokslot[tok];
  float4 ti = tokinfo[tok];
  f16x4 y0 = *(const f16x4*)(Y + (size_t)sl.x * CDIM + cc);
  f16x4 y1 = *(const f16x4*)(Y + (size_t)sl.y * CDIM + cc);
  float w0 = ti.z, w1 = ti.w;
  float4 o;
  o.x = w0 * (float)y0[0] + w1 * (float)y1[0];
  o.y = w0 * (float)y0[1] + w1 * (float)y1[1];
  o.z = w0 * (float)y0[2] + w1 * (float)y1[2];
  o.w = w0 * (float)y0[3] + w1 * (float)y1[3];
  *(float4*)(out + (size_t)tok * CDIM + cc) = o;
}

// ---------------- host ----------------

extern "C" void kernel_launch(void* const* d_in, const int* in_sizes, int n_in,
                              void* d_out, int out_size, void* d_ws, size_t ws_size,
                              hipStream_t stream) {
  const float* x  = (const float*)d_in[0];
  const float* gw = (const float*)d_in[1];
  const float* w1 = (const float*)d_in[2];
  const float* w2 = (const float*)d_in[3];
  float* out  = (float*)d_out;
  float* rout = out + (size_t)NTOK * CDIM;

  char* ws = (char*)d_ws;
  f16* xh      = (f16*)ws;      ws += (size_t)NTOK * CDIM * 2;       // 16.78 MB
  f16* w1t     = (f16*)ws;      ws += (size_t)NEXP * FF * CDIM * 2;  //  8.39 MB
  f16* w2t     = (f16*)ws;      ws += (size_t)NEXP * FF * CDIM * 2;  //  8.39 MB
  f16* Ybuf    = (f16*)ws;      ws += (size_t)CAP * CDIM * 2;        // 34.60 MB
  float4* tokinfo = (float4*)ws; ws += (size_t)NTOK * 16;            //  0.26 MB
  int2* tokslot = (int2*)ws;    ws += (size_t)NTOK * 8;              //  0.13 MB
  int* list    = (int*)ws;      ws += (size_t)CAP * 4;               //  0.14 MB
  int* cnt     = (int*)ws;      ws += 4 * CPAD * 4;
  int* base    = (int*)ws;      ws += 64;
  int* cursor  = (int*)ws;      ws += 4 * CPAD * 4;
  f16* Hbuf    = (f16*)ws;      // CB*128*FF f16, sized by ladder

  size_t base_bytes = (size_t)(ws - (char*)d_ws);
  const int opts[9] = {264, 132, 88, 44, 22, 12, 8, 4, 2};  // even divisors of 264
  int CB = 2;
  for (int oi = 0; oi < 9; ++oi) {
    if (base_bytes + (size_t)opts[oi] * BM * FF * 2 <= ws_size) { CB = opts[oi]; break; }
  }

  k_init<<<(CAP + 255) / 256, 256, 0, stream>>>(list, cnt);
  k_cast_t<<<dim3(FF / 64, CDIM / 64, NEXP), 256, 0, stream>>>(w1, w1t, CDIM, FF);
  k_cast_t<<<dim3(CDIM / 64, FF / 64, NEXP), 256, 0, stream>>>(w2, w2t, FF, CDIM);
  k_router<<<NTOK / 64, 256, 0, stream>>>(x, gw, xh, rout, tokinfo, cnt);
  k_bases<<<1, 64, 0, stream>>>(cnt, base, cursor);
  k_assign<<<NTOK / 1024, 256, 0, stream>>>(tokinfo, cursor, list, tokslot);

  for (int cb = 0; cb < NBLK; cb += CB) {
    int n1 = (CB / 2) * 16, n2 = (CB / 2) * 4;
    k_gemm1<<<n1, 512, 0, stream>>>(xh, w1t, list, base, Hbuf, cb, n1);
    k_gemm2<<<n2, 512, 0, stream>>>(Hbuf, w2t, base, Ybuf, cb, n2);
  }
  k_combine<<<NTOK * CDIM / 4 / 256, 256, 0, stream>>>(Ybuf, tokinfo, tokslot, out);
}

// Round 14
// 282.785 us; speedup vs baseline: 1.0119x; 1.0119x over previous
//
#include <hip/hip_runtime.h>
#include <hip/hip_fp16.h>

// DSMoE: x(8,2048,512) f32, gate_w(512,4), w1(4,512,2048), w2(4,2048,512)
// out = [ (8,2048,512) f32 ; router_sparse (16384,4) f32 ]
// R14: gemm2 -> fine-phase 3-slot-ring pipeline (T3+T4: 2 phases/K-tile,
//      16 MFMA/phase, counted vmcnt(4), barriers 4/K-tile). 256x256 tile,
//      8 waves of 128x64, BK=32. R6/R13 failed with COARSE counted-vmcnt
//      (m196: coarse hurts); the fine interleave is the untried lever.
//      gemm1 = R12 verbatim. Router 4x blocks. Fallback to R12-gemm2 if ws
//      can't hold CB=264.

#define NTOK  16384
#define CDIM  512
#define FF    2048
#define NEXP  4
#define CAP   33792    // 32768 + 4*256 (264 blocks of 128 / 132 of 256)
#define NBLK  264
#define BM    128
#define BN1   128
#define BK    32
#define NT2   64       // gemm2 K-tiles (2048/32)
#define CPAD  32

typedef _Float16 f16;
typedef __attribute__((ext_vector_type(8))) _Float16 f16x8;
typedef __attribute__((ext_vector_type(4))) _Float16 f16x4;
typedef __attribute__((ext_vector_type(4))) float f32x4;

__device__ __forceinline__ void gload16(const void* g, void* l) {
  __builtin_amdgcn_global_load_lds(
      (const __attribute__((address_space(1))) unsigned int*)g,
      (__attribute__((address_space(3))) unsigned int*)l, 16, 0, 0);
}

__device__ __forceinline__ float gelu_fast(float v) {
  float az = fabsf(v) * 0.7071067811865476f;
  float t = __builtin_amdgcn_rcpf(fmaf(0.3275911f, az, 1.0f));
  float p = fmaf(fmaf(fmaf(fmaf(1.061405429f, t, -1.453152027f), t,
                           1.421413741f), t, -0.284496736f), t, 0.254829592f) * t;
  float e = __builtin_amdgcn_exp2f(az * az * -1.4426950408889634f);
  float erfa = fmaf(-p, e, 1.0f);
  float u = copysignf(erfa, v);
  return 0.5f * v * (1.0f + u);
}

__device__ __forceinline__ int xcd_swz(int bid, int nwg) {
  int q = nwg >> 3, r = nwg & 7;
  int x = bid & 7, o = bid >> 3;
  return (x < r ? x * (q + 1) : r * (q + 1) + (x - r) * q) + o;
}

// ---------------- small utility kernels ----------------

__global__ __launch_bounds__(256) void k_init(int* list, int* cnt) {
  int i = blockIdx.x * 256 + threadIdx.x;
  if (i < CAP) list[i] = -1;
  if (i < 4) cnt[i * CPAD] = 0;
}

__global__ __launch_bounds__(256) void k_cast_t(const float* __restrict__ in,
                                                f16* __restrict__ out, int R, int Cc) {
  __shared__ f16 T[64][72];
  int ez = blockIdx.z;
  const float* ine = in + (size_t)ez * R * Cc;
  f16* oute = out + (size_t)ez * R * Cc;
  int c0 = blockIdx.x * 64;
  int r0 = blockIdx.y * 64;
  int t = threadIdx.x;
  {
    int rr = t >> 2, cc = (t & 3) * 16;
    const float* src = ine + (size_t)(r0 + rr) * Cc + c0 + cc;
    union { f16 h[16]; uint4 u[2]; } pk;
#pragma unroll
    for (int j = 0; j < 16; j += 4) {
      float4 a = *(const float4*)(src + j);
      pk.h[j] = (f16)a.x; pk.h[j + 1] = (f16)a.y;
      pk.h[j + 2] = (f16)a.z; pk.h[j + 3] = (f16)a.w;
    }
    *(uint4*)&T[rr][cc] = pk.u[0];
    *(uint4*)&T[rr][cc + 8] = pk.u[1];
  }
  __syncthreads();
  {
    int oc = t >> 2, orr = (t & 3) * 16;
    union { f16 h[16]; uint4 u[2]; } pk;
#pragma unroll
    for (int j = 0; j < 16; ++j) pk.h[j] = T[orr + j][oc];
    f16* dst = oute + (size_t)(c0 + oc) * R + r0 + orr;
    *(uint4*)dst = pk.u[0];
    *(uint4*)(dst + 8) = pk.u[1];
  }
}

// ---------------- router (fp32 exact) + fused x->fp16 cast ----------------
// 1024 blocks x 16 tokens (4 tokens/wave) for latency hiding.

__global__ __launch_bounds__(256) void k_router(const float* __restrict__ x,
                                                const float* __restrict__ gw,
                                                f16* __restrict__ xh,
                                                float* __restrict__ rout,
                                                float4* __restrict__ tokinfo,
                                                int* __restrict__ cnt) {
  __shared__ int lcnt[4];
  int tid = threadIdx.x;
  if (tid < 4) lcnt[tid] = 0;
  __syncthreads();
  int wv = tid >> 6, lane = tid & 63;
  const float4* g = ((const float4*)gw) + lane * 8;
  float4 gv[8];
#pragma unroll
  for (int j = 0; j < 8; ++j) gv[j] = g[j];

  int tok0 = blockIdx.x * 16 + wv * 4;
  for (int i = 0; i < 4; ++i) {
    int tok = tok0 + i;
    const float4* xr = (const float4*)(x + (size_t)tok * CDIM + lane * 8);
    float4 a0 = xr[0], a1 = xr[1];
    union { f16 h[8]; uint4 u; } pk;
    pk.h[0] = (f16)a0.x; pk.h[1] = (f16)a0.y; pk.h[2] = (f16)a0.z; pk.h[3] = (f16)a0.w;
    pk.h[4] = (f16)a1.x; pk.h[5] = (f16)a1.y; pk.h[6] = (f16)a1.z; pk.h[7] = (f16)a1.w;
    *(uint4*)(xh + (size_t)tok * CDIM + lane * 8) = pk.u;
    float xv[8] = {a0.x, a0.y, a0.z, a0.w, a1.x, a1.y, a1.z, a1.w};
    float l0 = 0, l1 = 0, l2 = 0, l3 = 0;
#pragma unroll
    for (int j = 0; j < 8; ++j) {
      float4 g4 = gv[j];
      l0 = fmaf(xv[j], g4.x, l0); l1 = fmaf(xv[j], g4.y, l1);
      l2 = fmaf(xv[j], g4.z, l2); l3 = fmaf(xv[j], g4.w, l3);
    }
#pragma unroll
    for (int off = 32; off; off >>= 1) {
      l0 += __shfl_xor(l0, off); l1 += __shfl_xor(l1, off);
      l2 += __shfl_xor(l2, off); l3 += __shfl_xor(l3, off);
    }
    if (lane == 0) {
      float lg[4] = {l0, l1, l2, l3};
      float m = fmaxf(fmaxf(lg[0], lg[1]), fmaxf(lg[2], lg[3]));
      float p[4], s = 0.f;
#pragma unroll
      for (int e = 0; e < 4; ++e) { p[e] = expf(lg[e] - m); s += p[e]; }
      int i0 = 0;
#pragma unroll
      for (int e = 1; e < 4; ++e) if (lg[e] > lg[i0]) i0 = e;
      int i1 = -1;
#pragma unroll
      for (int e = 0; e < 4; ++e)
        if (e != i0 && (i1 < 0 || lg[e] > lg[i1])) i1 = e;
      float p0 = p[i0] / s, p1 = p[i1] / s;
      float ss = fmaxf(p0 + p1, 1e-6f);
      float w0 = p0 / ss, w1v = p1 / ss;
      float r[4] = {0.f, 0.f, 0.f, 0.f};
      r[i0] = w0; r[i1] = w1v;
      *(float4*)(rout + tok * 4) = make_float4(r[0], r[1], r[2], r[3]);
      float4 ti;
      ti.x = __int_as_float(i0); ti.y = __int_as_float(i1); ti.z = w0; ti.w = w1v;
      tokinfo[tok] = ti;
      atomicAdd(&lcnt[i0], 1);
      atomicAdd(&lcnt[i1], 1);
    }
  }
  __syncthreads();
  if (tid < 4) atomicAdd(cnt + tid * CPAD, lcnt[tid]);
}

__global__ void k_bases(const int* __restrict__ cnt, int* __restrict__ base,
                        int* __restrict__ cursor) {
  if (threadIdx.x == 0 && blockIdx.x == 0) {
    int b = 0;
#pragma unroll
    for (int e = 0; e < 4; ++e) {
      base[e] = b; cursor[e * CPAD] = b;
      b += (cnt[e * CPAD] + 255) & ~255;   // 256-aligned regions
    }
    base[4] = b;
  }
}

__global__ __launch_bounds__(256) void k_assign(const float4* __restrict__ tokinfo,
                                                int* cursor, int* __restrict__ list,
                                                int2* __restrict__ tokslot) {
  __shared__ int lcnt[4], lbase[4];
  int tid = threadIdx.x;
  if (tid < 4) lcnt[tid] = 0;
  __syncthreads();
  int t0 = blockIdx.x * 1024 + tid * 4;
  float4 ti[4]; int lo0[4], lo1[4];
#pragma unroll
  for (int j = 0; j < 4; ++j) {
    ti[j] = tokinfo[t0 + j];
    lo0[j] = atomicAdd(&lcnt[__float_as_int(ti[j].x)], 1);
    lo1[j] = atomicAdd(&lcnt[__float_as_int(ti[j].y)], 1);
  }
  __syncthreads();
  if (tid < 4) lbase[tid] = atomicAdd(cursor + tid * CPAD, lcnt[tid]);
  __syncthreads();
#pragma unroll
  for (int j = 0; j < 4; ++j) {
    int s0 = lbase[__float_as_int(ti[j].x)] + lo0[j];
    list[s0] = t0 + j;
    int s1 = lbase[__float_as_int(ti[j].y)] + lo1[j];
    list[s1] = t0 + j;
    tokslot[t0 + j] = make_int2(s0, s1);
  }
}

// ---------------- pass 1: H[slot, :] = gelu(x[list] @ W1e) ----------------
// R12 verbatim: 128x128, BK=32, dbuf, 4 blk/CU, stage-early + syncthreads.

__global__ __launch_bounds__(256, 4) void k_gemm1(const f16* __restrict__ xh,
                                                  const f16* __restrict__ w1t,
                                                  const int* __restrict__ list,
                                                  const int* __restrict__ base,
                                                  f16* __restrict__ H, int cb, int nwg) {
  __shared__ __align__(16) char smem[32768 + 512];
  int* slist = (int*)(smem + 32768);
  int tid = threadIdx.x;
  int wk = xcd_swz(blockIdx.x, nwg);
  int bx = wk >> 4, by = wk & 15;
  int m0 = (cb + bx) * BM;
  int mloc = bx * BM;
  int h0 = by * BN1;
  int e = 0;
#pragma unroll
  for (int i = 1; i < 4; ++i) if (m0 >= base[i]) e = i;
  if (tid < BM) {
    int v = list[m0 + tid];
    slist[tid] = v < 0 ? 0 : v;
  }
  __syncthreads();

  int tokr[2];
#pragma unroll
  for (int i = 0; i < 2; ++i) tokr[i] = slist[i * 64 + (tid >> 2)];

  const f16* wB = w1t + (size_t)(e * FF + h0) * CDIM;
  int kbs = ((tid & 3) * 16) ^ (((tid >> 3) & 3) << 4);

  f32x4 acc[4][4] = {};
  int lane = tid & 63, w = tid >> 6, wr = w >> 1, wc = w & 1;

  auto stage = [&](int kk, int p) {
    char* s = smem + p * 16384;
#pragma unroll
    for (int i = 0; i < 2; ++i) {
      gload16(xh + (size_t)tokr[i] * CDIM + kk * BK + (kbs >> 1),
              s + i * 4096 + tid * 16);
    }
#pragma unroll
    for (int i = 0; i < 2; ++i) {
      int row = i * 64 + (tid >> 2);
      gload16(wB + (size_t)row * CDIM + kk * BK + (kbs >> 1),
              s + 8192 + i * 4096 + tid * 16);
    }
  };

  auto compute = [&](int p) {
    const char* s = smem + p * 16384;
    f16x8 af[4], bfr[4];
    int kb = (lane >> 4) * 16;
#pragma unroll
    for (int fr = 0; fr < 4; ++fr) {
      int row = wr * 64 + fr * 16 + (lane & 15);
      af[fr] = *(const f16x8*)(s + row * 64 + (kb ^ (((row >> 1) & 3) << 4)));
    }
#pragma unroll
    for (int fc = 0; fc < 4; ++fc) {
      int col = wc * 64 + fc * 16 + (lane & 15);
      bfr[fc] = *(const f16x8*)(s + 8192 + col * 64 + (kb ^ (((col >> 1) & 3) << 4)));
    }
#pragma unroll
    for (int fr = 0; fr < 4; ++fr)
#pragma unroll
      for (int fc = 0; fc < 4; ++fc)
        acc[fr][fc] = __builtin_amdgcn_mfma_f32_16x16x32_f16(af[fr], bfr[fc],
                                                             acc[fr][fc], 0, 0, 0);
  };

  stage(0, 0);
  __syncthreads();
  for (int kk = 0; kk < 16; ++kk) {
    if (kk < 15) stage(kk + 1, (kk + 1) & 1);
    __builtin_amdgcn_sched_barrier(0);
    __builtin_amdgcn_s_setprio(1);
    compute(kk & 1);
    __builtin_amdgcn_s_setprio(0);
    __syncthreads();
  }

#pragma unroll
  for (int fr = 0; fr < 4; ++fr)
#pragma unroll
    for (int fc = 0; fc < 4; ++fc)
#pragma unroll
      for (int i = 0; i < 4; ++i) {
        int row = wr * 64 + fr * 16 + (lane >> 4) * 4 + i;
        int col = wc * 64 + fc * 16 + (lane & 15);
        float v = gelu_fast(acc[fr][fc][i]);
        int off = (row * 256 + col * 2) ^ ((row & 7) << 4);
        *(f16*)(smem + off) = (f16)v;
      }
  __syncthreads();
#pragma unroll
  for (int j = 0; j < 8; ++j) {
    int row = j * 16 + (tid >> 4);
    int colb = ((tid & 15) * 16) ^ ((row & 7) << 4);
    uint4 v = *(const uint4*)(smem + row * 256 + colb);
    *(uint4*)((char*)H + ((size_t)(mloc + row) * FF + h0) * 2 + (tid & 15) * 16) = v;
  }
}

// ------- pass 2 (fine-phase): Y = H @ W2e, 256x256 tile, 3-slot ring -------
// 512 thr, 8 waves of 128x64. Per K-tile(32): 2 phases x {ds_reads | 2 gloads
// staging kt+2 -> barrier -> lgkmcnt(0) -> 16 MFMA -> barrier}; vmcnt(4) once
// per K-tile. Ring slots (kt%3) make stage targets disjoint from live slots.

__global__ __launch_bounds__(512, 2) void k_gemm2r(const f16* __restrict__ H,
                                                   const f16* __restrict__ w2t,
                                                   const int* __restrict__ base,
                                                   f16* __restrict__ Y, int nwg) {
  __shared__ __align__(16) char smem[131072];   // pipeline 3x32KB; epilogue 128KB
  int tid = threadIdx.x;
  int wk = xcd_swz(blockIdx.x, nwg);
  int bx = wk >> 1, by = wk & 1;
  int m0 = bx * 256;
  int c0 = by * 256;
  int e = 0;
#pragma unroll
  for (int i = 1; i < 4; ++i) if (m0 >= base[i]) e = i;

  const f16* pA = H + (size_t)m0 * FF;
  const f16* wB = w2t + (size_t)(e * CDIM + c0) * FF;
  int kbs = ((tid & 3) * 16) ^ (((tid >> 3) & 3) << 4);

  f32x4 acc[8][4] = {};
  int lane = tid & 63, w = tid >> 6, wr = w >> 2, wc = w & 3;

  // precomputed swizzled LDS read offsets (bytes within a slot)
  int kb = (lane >> 4) * 16;
  int aoff[8], boff[4];
#pragma unroll
  for (int fr = 0; fr < 8; ++fr) {
    int row = wr * 128 + fr * 16 + (lane & 15);
    aoff[fr] = row * 64 + (kb ^ (((row >> 1) & 3) << 4));
  }
#pragma unroll
  for (int fc = 0; fc < 4; ++fc) {
    int col = wc * 64 + fc * 16 + (lane & 15);
    boff[fc] = 16384 + col * 64 + (kb ^ (((col >> 1) & 3) << 4));
  }

  auto stageA = [&](int kt, int sb) {   // 2 gloads: 256 rows x 32 k
    char* s = smem + sb;
#pragma unroll
    for (int l = 0; l < 2; ++l) {
      int row = l * 128 + (tid >> 2);
      gload16(pA + (size_t)row * FF + kt * BK + (kbs >> 1), s + l * 8192 + tid * 16);
    }
  };
  auto stageB = [&](int kt, int sb) {   // 2 gloads: 256 cols x 32 k
    char* s = smem + sb + 16384;
#pragma unroll
    for (int l = 0; l < 2; ++l) {
      int row = l * 128 + (tid >> 2);
      gload16(wB + (size_t)row * FF + kt * BK + (kbs >> 1), s + l * 8192 + tid * 16);
    }
  };

  // prologue: stage kt0 -> slot0, kt1 -> slot1; verify kt0 landed
  stageA(0, 0); stageB(0, 0);
  stageA(1, 32768); stageB(1, 32768);
  asm volatile("s_waitcnt vmcnt(4)" ::: "memory");
  __builtin_amdgcn_s_barrier();

  int scur = 0, sst = 65536;   // read slot, stage slot (kt+2)
  f16x8 af[4], bf[4];
  for (int kt = 0; kt < NT2; ++kt) {
    const char* s = smem + scur;
    // ---- phase 1: A[0-3], B[0-3] reads; stage A(kt+2); MFMA fr0-3 ----
#pragma unroll
    for (int fc = 0; fc < 4; ++fc) bf[fc] = *(const f16x8*)(s + boff[fc]);
#pragma unroll
    for (int fr = 0; fr < 4; ++fr) af[fr] = *(const f16x8*)(s + aoff[fr]);
    if (kt < NT2 - 2) stageA(kt + 2, sst);
    __builtin_amdgcn_s_barrier();
    asm volatile("s_waitcnt lgkmcnt(0)" ::: "memory");
    __builtin_amdgcn_sched_barrier(0);
    __builtin_amdgcn_s_setprio(1);
#pragma unroll
    for (int fr = 0; fr < 4; ++fr)
#pragma unroll
      for (int fc = 0; fc < 4; ++fc)
        acc[fr][fc] = __builtin_amdgcn_mfma_f32_16x16x32_f16(af[fr], bf[fc],
                                                             acc[fr][fc], 0, 0, 0);
    __builtin_amdgcn_s_setprio(0);
    __builtin_amdgcn_sched_barrier(0);
    __builtin_amdgcn_s_barrier();
    // ---- phase 2: A[4-7] reads; stage B(kt+2); verify kt+1; MFMA fr4-7 ----
#pragma unroll
    for (int fr = 0; fr < 4; ++fr) af[fr] = *(const f16x8*)(s + aoff[4 + fr]);
    if (kt < NT2 - 2) {
      stageB(kt + 2, sst);
      asm volatile("s_waitcnt vmcnt(4)" ::: "memory");   // kt+1 fully landed
    } else {
      asm volatile("s_waitcnt vmcnt(0)" ::: "memory");   // tail drain
    }
    __builtin_amdgcn_s_barrier();
    asm volatile("s_waitcnt lgkmcnt(0)" ::: "memory");
    __builtin_amdgcn_sched_barrier(0);
    __builtin_amdgcn_s_setprio(1);
#pragma unroll
    for (int fr = 0; fr < 4; ++fr)
#pragma unroll
      for (int fc = 0; fc < 4; ++fc)
        acc[4 + fr][fc] = __builtin_amdgcn_mfma_f32_16x16x32_f16(af[fr], bf[fc],
                                                                 acc[4 + fr][fc], 0, 0, 0);
    __builtin_amdgcn_s_setprio(0);
    __builtin_amdgcn_sched_barrier(0);
    __builtin_amdgcn_s_barrier();
    scur = (scur == 65536) ? 0 : scur + 32768;
    sst  = (sst  == 65536) ? 0 : sst  + 32768;
  }

  // epilogue: f16 -> LDS repack [256][512B] (XOR<<4) -> coalesced 16B stores
#pragma unroll
  for (int fr = 0; fr < 8; ++fr)
#pragma unroll
    for (int fc = 0; fc < 4; ++fc)
#pragma unroll
      for (int i = 0; i < 4; ++i) {
        int row = wr * 128 + fr * 16 + (lane >> 4) * 4 + i;
        int col = wc * 64 + fc * 16 + (lane & 15);
        int off = row * 512 + ((col * 2) ^ ((row & 7) << 4));
        *(f16*)(smem + off) = (f16)acc[fr][fc][i];
      }
  __syncthreads();
#pragma unroll
  for (int j = 0; j < 16; ++j) {
    int row = j * 16 + (tid >> 5);
    int colb = ((tid & 31) * 16) ^ ((row & 7) << 4);
    uint4 v = *(const uint4*)(smem + row * 512 + colb);
    *(uint4*)((char*)Y + ((size_t)(m0 + row) * CDIM + c0) * 2 + (tid & 31) * 16) = v;
  }
}

// ---------------- legacy pass 2 (R12) — fallback when ws forces chunks ----

__global__ __launch_bounds__(256, 4) void k_gemm2(const f16* __restrict__ H,
                                                  const f16* __restrict__ w2t,
                                                  const int* __restrict__ base,
                                                  f16* __restrict__ Y, int cb, int nwg) {
  __shared__ __align__(16) char smem[32768];
  int tid = threadIdx.x;
  int wk = xcd_swz(blockIdx.x, nwg);
  int bx = wk >> 2, by = wk & 3;
  int m0 = (cb + bx) * BM;
  int mloc = bx * BM;
  int c0 = by * 128;
  int e = 0;
#pragma unroll
  for (int i = 1; i < 4; ++i) if (m0 >= base[i]) e = i;

  const f16* pA = H + (size_t)mloc * FF;
  const f16* wB = w2t + (size_t)(e * CDIM + c0) * FF;
  int kbs = ((tid & 3) * 16) ^ (((tid >> 3) & 3) << 4);

  f32x4 acc[4][4] = {};
  int lane = tid & 63, w = tid >> 6, wr = w >> 1, wc = w & 1;

  auto stage = [&](int kk, int p) {
    char* s = smem + p * 16384;
#pragma unroll
    for (int i = 0; i < 2; ++i) {
      int row = i * 64 + (tid >> 2);
      gload16(pA + (size_t)row * FF + kk * BK + (kbs >> 1),
              s + i * 4096 + tid * 16);
    }
#pragma unroll
    for (int i = 0; i < 2; ++i) {
      int row = i * 64 + (tid >> 2);
      gload16(wB + (size_t)row * FF + kk * BK + (kbs >> 1),
              s + 8192 + i * 4096 + tid * 16);
    }
  };

  auto compute = [&](int p) {
    const char* s = smem + p * 16384;
    f16x8 af[4], bfr[4];
    int kb = (lane >> 4) * 16;
#pragma unroll
    for (int fr = 0; fr < 4; ++fr) {
      int row = wr * 64 + fr * 16 + (lane & 15);
      af[fr] = *(const f16x8*)(s + row * 64 + (kb ^ (((row >> 1) & 3) << 4)));
    }
#pragma unroll
    for (int fc = 0; fc < 4; ++fc) {
      int col = wc * 64 + fc * 16 + (lane & 15);
      bfr[fc] = *(const f16x8*)(s + 8192 + col * 64 + (kb ^ (((col >> 1) & 3) << 4)));
    }
#pragma unroll
    for (int fr = 0; fr < 4; ++fr)
#pragma unroll
      for (int fc = 0; fc < 4; ++fc)
        acc[fr][fc] = __builtin_amdgcn_mfma_f32_16x16x32_f16(af[fr], bfr[fc],
                                                             acc[fr][fc], 0, 0, 0);
  };

  stage(0, 0);
  __syncthreads();
  for (int kk = 0; kk < 64; ++kk) {
    if (kk < 63) stage(kk + 1, (kk + 1) & 1);
    __builtin_amdgcn_sched_barrier(0);
    __builtin_amdgcn_s_setprio(1);
    compute(kk & 1);
    __builtin_amdgcn_s_setprio(0);
    __syncthreads();
  }

#pragma unroll
  for (int fr = 0; fr < 4; ++fr)
#pragma unroll
    for (int fc = 0; fc < 4; ++fc)
#pragma unroll
      for (int i = 0; i < 4; ++i) {
        int row = wr * 64 + fr * 16 + (lane >> 4) * 4 + i;
        int col = wc * 64 + fc * 16 + (lane & 15);
        int off = (row * 256 + col * 2) ^ ((row & 7) << 4);
        *(f16*)(smem + off) = (f16)acc[fr][fc][i];
      }
  __syncthreads();
#pragma unroll
  for (int j = 0; j < 8; ++j) {
    int row = j * 16 + (tid >> 4);
    int colb = ((tid & 15) * 16) ^ ((row & 7) << 4);
    uint4 v = *(const uint4*)(smem + row * 256 + colb);
    *(uint4*)((char*)Y + ((size_t)(m0 + row) * CDIM + c0) * 2 + (tid & 15) * 16) = v;
  }
}

// ---------------- combine: out[tok] = w0*Y[s0] + w1*Y[s1] ----------------

__global__ __launch_bounds__(256) void k_combine(const f16* __restrict__ Y,
                                                 const float4* __restrict__ tokinfo,
                                                 const int2* __restrict__ tokslot,
                                                 float* __restrict__ out) {
  int gid = blockIdx.x * 256 + threadIdx.x;
  int tok = gid >> 7;
  int cc = (gid & 127) * 4;
  int2 sl = tokslot[tok];
  float4 ti = tokinfo[tok];
  f16x4 y0 = *(const f16x4*)(Y + (size_t)sl.x * CDIM + cc);
  f16x4 y1 = *(const f16x4*)(Y + (size_t)sl.y * CDIM + cc);
  float w0 = ti.z, w1 = ti.w;
  float4 o;
  o.x = w0 * (float)y0[0] + w1 * (float)y1[0];
  o.y = w0 * (float)y0[1] + w1 * (float)y1[1];
  o.z = w0 * (float)y0[2] + w1 * (float)y1[2];
  o.w = w0 * (float)y0[3] + w1 * (float)y1[3];
  *(float4*)(out + (size_t)tok * CDIM + cc) = o;
}

// ---------------- host ----------------

extern "C" void kernel_launch(void* const* d_in, const int* in_sizes, int n_in,
                              void* d_out, int out_size, void* d_ws, size_t ws_size,
                              hipStream_t stream) {
  const float* x  = (const float*)d_in[0];
  const float* gw = (const float*)d_in[1];
  const float* w1 = (const float*)d_in[2];
  const float* w2 = (const float*)d_in[3];
  float* out  = (float*)d_out;
  float* rout = out + (size_t)NTOK * CDIM;

  char* ws = (char*)d_ws;
  f16* xh      = (f16*)ws;      ws += (size_t)NTOK * CDIM * 2;
  f16* w1t     = (f16*)ws;      ws += (size_t)NEXP * FF * CDIM * 2;
  f16* w2t     = (f16*)ws;      ws += (size_t)NEXP * FF * CDIM * 2;
  f16* Ybuf    = (f16*)ws;      ws += (size_t)CAP * CDIM * 2;
  float4* tokinfo = (float4*)ws; ws += (size_t)NTOK * 16;
  int2* tokslot = (int2*)ws;    ws += (size_t)NTOK * 8;
  int* list    = (int*)ws;      ws += (size_t)CAP * 4;
  int* cnt     = (int*)ws;      ws += 4 * CPAD * 4;
  int* base    = (int*)ws;      ws += 64;
  int* cursor  = (int*)ws;      ws += 4 * CPAD * 4;
  f16* Hbuf    = (f16*)ws;

  size_t base_bytes = (size_t)(ws - (char*)d_ws);
  const int opts[9] = {264, 132, 88, 44, 22, 12, 8, 4, 2};
  int CB = 2;
  for (int oi = 0; oi < 9; ++oi) {
    if (base_bytes + (size_t)opts[oi] * BM * FF * 2 <= ws_size) { CB = opts[oi]; break; }
  }

  k_init<<<(CAP + 255) / 256, 256, 0, stream>>>(list, cnt);
  k_cast_t<<<dim3(FF / 64, CDIM / 64, NEXP), 256, 0, stream>>>(w1, w1t, CDIM, FF);
  k_cast_t<<<dim3(CDIM / 64, FF / 64, NEXP), 256, 0, stream>>>(w2, w2t, FF, CDIM);
  k_router<<<NTOK / 16, 256, 0, stream>>>(x, gw, xh, rout, tokinfo, cnt);
  k_bases<<<1, 64, 0, stream>>>(cnt, base, cursor);
  k_assign<<<NTOK / 1024, 256, 0, stream>>>(tokinfo, cursor, list, tokslot);

  if (CB == NBLK) {
    // single chunk: fine-phase gemm2 on the whole slot range
    int n1 = NBLK * 16;
    k_gemm1<<<n1, 256, 0, stream>>>(xh, w1t, list, base, Hbuf, 0, n1);
    int n2 = (NBLK / 2) * 2;   // 264 blocks: 132 bx x 2 by
    k_gemm2r<<<n2, 512, 0, stream>>>(Hbuf, w2t, base, Ybuf, n2);
  } else {
    for (int cb = 0; cb < NBLK; cb += CB) {
      int n1 = CB * 16, n2 = CB * 4;
      k_gemm1<<<n1, 256, 0, stream>>>(xh, w1t, list, base, Hbuf, cb, n1);
      k_gemm2<<<n2, 256, 0, stream>>>(Hbuf, w2t, base, Ybuf, cb, n2);
    }
  }
  k_combine<<<NTOK * CDIM / 4 / 256, 256, 0, stream>>>(Ybuf, tokinfo, tokslot, out);
}

// Round 15
// 255.212 us; speedup vs baseline: 1.1212x; 1.1080x over previous
//
#include <hip/hip_runtime.h>
#include <hip/hip_fp16.h>

// DSMoE: x(8,2048,512) f32, gate_w(512,4), w1(4,512,2048), w2(4,2048,512)
// out = [ (8,2048,512) f32 ; router_sparse (16384,4) f32 ]
// R15: R12 GEMMs verbatim (best, 264.5us); overhead trims: k_init deleted
//      (router -> per-block counts, k_bases reduces + pad-fills), cast_t
//      fused to one dispatch, router 1024 blocks, combine 16B-widened.
//      R6/R13/R14 lesson: deep-pipeline variants all lose to 2-phase dbuf
//      @4blk/CU at these shapes.

#define NTOK  16384
#define CDIM  512
#define FF    2048
#define NEXP  4
#define CAP   33280    // 32768 + 4*128 padding headroom (260 blocks of 128)
#define NBLK  260
#define BM    128
#define BN1   128
#define BN2   128
#define BK    32
#define CPAD  32
#define RBLK  1024     // router blocks (16 tokens each)

typedef _Float16 f16;
typedef __attribute__((ext_vector_type(8))) _Float16 f16x8;
typedef __attribute__((ext_vector_type(4))) _Float16 f16x4;
typedef __attribute__((ext_vector_type(4))) float f32x4;

__device__ __forceinline__ void gload16(const void* g, void* l) {
  __builtin_amdgcn_global_load_lds(
      (const __attribute__((address_space(1))) unsigned int*)g,
      (__attribute__((address_space(3))) unsigned int*)l, 16, 0, 0);
}

// gelu(v) = 0.5 v (1 + erf(v/sqrt2)), erf via Abramowitz-Stegun 7.1.26
__device__ __forceinline__ float gelu_fast(float v) {
  float az = fabsf(v) * 0.7071067811865476f;
  float t = __builtin_amdgcn_rcpf(fmaf(0.3275911f, az, 1.0f));
  float p = fmaf(fmaf(fmaf(fmaf(1.061405429f, t, -1.453152027f), t,
                           1.421413741f), t, -0.284496736f), t, 0.254829592f) * t;
  float e = __builtin_amdgcn_exp2f(az * az * -1.4426950408889634f);
  float erfa = fmaf(-p, e, 1.0f);
  float u = copysignf(erfa, v);
  return 0.5f * v * (1.0f + u);
}

// bijective XCD swizzle for any nwg (m204 form)
__device__ __forceinline__ int xcd_swz(int bid, int nwg) {
  int q = nwg >> 3, r = nwg & 7;
  int x = bid & 7, o = bid >> 3;
  return (x < r ? x * (q + 1) : r * (q + 1) + (x - r) * q) + o;
}

// ---------------- fused transpose-cast: w1 (z<4) and w2 (z>=4) ----------------
// w1: in [E][CDIM][FF] -> out [E][FF][CDIM]; w2: in [E][FF][CDIM] -> out [E][CDIM][FF]

__global__ __launch_bounds__(256) void k_cast_t2(const float* __restrict__ w1,
                                                 f16* __restrict__ w1t,
                                                 const float* __restrict__ w2,
                                                 f16* __restrict__ w2t) {
  __shared__ f16 T[64][72];
  int z = blockIdx.z;
  const float* in; f16* out; int R, Cc, ez, c0, r0;
  if (z < 4) { in = w1; out = w1t; R = CDIM; Cc = FF; ez = z;
               c0 = blockIdx.x * 64; r0 = blockIdx.y * 64; }
  else       { in = w2; out = w2t; R = FF; Cc = CDIM; ez = z - 4;
               c0 = blockIdx.y * 64; r0 = blockIdx.x * 64; }
  const float* ine = in + (size_t)ez * R * Cc;
  f16* oute = out + (size_t)ez * R * Cc;
  int t = threadIdx.x;
  {
    int rr = t >> 2, cc = (t & 3) * 16;
    const float* src = ine + (size_t)(r0 + rr) * Cc + c0 + cc;
    union { f16 h[16]; uint4 u[2]; } pk;
#pragma unroll
    for (int j = 0; j < 16; j += 4) {
      float4 a = *(const float4*)(src + j);
      pk.h[j] = (f16)a.x; pk.h[j + 1] = (f16)a.y;
      pk.h[j + 2] = (f16)a.z; pk.h[j + 3] = (f16)a.w;
    }
    *(uint4*)&T[rr][cc] = pk.u[0];
    *(uint4*)&T[rr][cc + 8] = pk.u[1];
  }
  __syncthreads();
  {
    int oc = t >> 2, orr = (t & 3) * 16;
    union { f16 h[16]; uint4 u[2]; } pk;
#pragma unroll
    for (int j = 0; j < 16; ++j) pk.h[j] = T[orr + j][oc];
    f16* dst = oute + (size_t)(c0 + oc) * R + r0 + orr;
    *(uint4*)dst = pk.u[0];
    *(uint4*)(dst + 8) = pk.u[1];
  }
}

// ---------------- router (fp32 exact) + fused x->fp16 cast ----------------
// 1024 blocks x 16 tokens; per-block counts (NO global atomics).

__global__ __launch_bounds__(256) void k_router(const float* __restrict__ x,
                                                const float* __restrict__ gw,
                                                f16* __restrict__ xh,
                                                float* __restrict__ rout,
                                                float4* __restrict__ tokinfo,
                                                int* __restrict__ bcnt) {
  __shared__ int lcnt[4];
  int tid = threadIdx.x;
  if (tid < 4) lcnt[tid] = 0;
  __syncthreads();
  int wv = tid >> 6, lane = tid & 63;
  const float4* g = ((const float4*)gw) + lane * 8;
  float4 gv[8];
#pragma unroll
  for (int j = 0; j < 8; ++j) gv[j] = g[j];

  int tok0 = blockIdx.x * 16 + wv * 4;
  for (int i = 0; i < 4; ++i) {
    int tok = tok0 + i;
    const float4* xr = (const float4*)(x + (size_t)tok * CDIM + lane * 8);
    float4 a0 = xr[0], a1 = xr[1];
    union { f16 h[8]; uint4 u; } pk;
    pk.h[0] = (f16)a0.x; pk.h[1] = (f16)a0.y; pk.h[2] = (f16)a0.z; pk.h[3] = (f16)a0.w;
    pk.h[4] = (f16)a1.x; pk.h[5] = (f16)a1.y; pk.h[6] = (f16)a1.z; pk.h[7] = (f16)a1.w;
    *(uint4*)(xh + (size_t)tok * CDIM + lane * 8) = pk.u;
    float xv[8] = {a0.x, a0.y, a0.z, a0.w, a1.x, a1.y, a1.z, a1.w};
    float l0 = 0, l1 = 0, l2 = 0, l3 = 0;
#pragma unroll
    for (int j = 0; j < 8; ++j) {
      float4 g4 = gv[j];
      l0 = fmaf(xv[j], g4.x, l0); l1 = fmaf(xv[j], g4.y, l1);
      l2 = fmaf(xv[j], g4.z, l2); l3 = fmaf(xv[j], g4.w, l3);
    }
#pragma unroll
    for (int off = 32; off; off >>= 1) {
      l0 += __shfl_xor(l0, off); l1 += __shfl_xor(l1, off);
      l2 += __shfl_xor(l2, off); l3 += __shfl_xor(l3, off);
    }
    if (lane == 0) {
      float lg[4] = {l0, l1, l2, l3};
      float m = fmaxf(fmaxf(lg[0], lg[1]), fmaxf(lg[2], lg[3]));
      float p[4], s = 0.f;
#pragma unroll
      for (int e = 0; e < 4; ++e) { p[e] = expf(lg[e] - m); s += p[e]; }
      int i0 = 0;
#pragma unroll
      for (int e = 1; e < 4; ++e) if (lg[e] > lg[i0]) i0 = e;   // ties -> lower idx
      int i1 = -1;
#pragma unroll
      for (int e = 0; e < 4; ++e)
        if (e != i0 && (i1 < 0 || lg[e] > lg[i1])) i1 = e;
      float p0 = p[i0] / s, p1 = p[i1] / s;
      float ss = fmaxf(p0 + p1, 1e-6f);
      float w0 = p0 / ss, w1v = p1 / ss;
      float r[4] = {0.f, 0.f, 0.f, 0.f};
      r[i0] = w0; r[i1] = w1v;
      *(float4*)(rout + tok * 4) = make_float4(r[0], r[1], r[2], r[3]);
      float4 ti;
      ti.x = __int_as_float(i0); ti.y = __int_as_float(i1); ti.z = w0; ti.w = w1v;
      tokinfo[tok] = ti;
      atomicAdd(&lcnt[i0], 1);
      atomicAdd(&lcnt[i1], 1);
    }
  }
  __syncthreads();
  if (tid < 4) bcnt[blockIdx.x * 4 + tid] = lcnt[tid];   // plain store, no atomics
}

// 1 block: reduce per-block counts, compute 128-aligned bases, pad-fill list.
__global__ __launch_bounds__(256) void k_bases(const int* __restrict__ bcnt,
                                               int* __restrict__ base,
                                               int* __restrict__ cursor,
                                               int* __restrict__ list) {
  __shared__ int tot[4], lb[5];
  int tid = threadIdx.x;
  if (tid < 4) tot[tid] = 0;
  __syncthreads();
  int acc[4] = {0, 0, 0, 0};
  for (int i = tid; i < RBLK; i += 256) {
    const int4 v = *(const int4*)(bcnt + i * 4);
    acc[0] += v.x; acc[1] += v.y; acc[2] += v.z; acc[3] += v.w;
  }
#pragma unroll
  for (int e = 0; e < 4; ++e) atomicAdd(&tot[e], acc[e]);
  __syncthreads();
  if (tid == 0) {
    int b = 0;
#pragma unroll
    for (int e = 0; e < 4; ++e) {
      lb[e] = b; base[e] = b; cursor[e * CPAD] = b;
      b += (tot[e] + 127) & ~127;
    }
    lb[4] = b; base[4] = b;
  }
  __syncthreads();
#pragma unroll
  for (int e = 0; e < 4; ++e) {
    int s = lb[e] + tot[e], end = lb[e + 1];
    for (int i = s + tid; i < end; i += 256) list[i] = -1;   // pad slots
  }
}

// slot assignment + inverse map (token -> its 2 slots)
__global__ __launch_bounds__(256) void k_assign(const float4* __restrict__ tokinfo,
                                                int* cursor, int* __restrict__ list,
                                                int2* __restrict__ tokslot) {
  __shared__ int lcnt[4], lbase[4];
  int tid = threadIdx.x;
  if (tid < 4) lcnt[tid] = 0;
  __syncthreads();
  int t0 = blockIdx.x * 1024 + tid * 4;
  float4 ti[4]; int lo0[4], lo1[4];
#pragma unroll
  for (int j = 0; j < 4; ++j) {
    ti[j] = tokinfo[t0 + j];
    lo0[j] = atomicAdd(&lcnt[__float_as_int(ti[j].x)], 1);
    lo1[j] = atomicAdd(&lcnt[__float_as_int(ti[j].y)], 1);
  }
  __syncthreads();
  if (tid < 4) lbase[tid] = atomicAdd(cursor + tid * CPAD, lcnt[tid]);
  __syncthreads();
#pragma unroll
  for (int j = 0; j < 4; ++j) {
    int s0 = lbase[__float_as_int(ti[j].x)] + lo0[j];
    list[s0] = t0 + j;
    int s1 = lbase[__float_as_int(ti[j].y)] + lo1[j];
    list[s1] = t0 + j;
    tokslot[t0 + j] = make_int2(s0, s1);
  }
}

// ---------------- pass 1: H[slot, :] = gelu(x[list] @ W1e) ----------------
// R12 verbatim: 128x128, BK=32, dbuf 2x16KB, 4 blk/CU, stage-early + syncthreads.

__global__ __launch_bounds__(256, 4) void k_gemm1(const f16* __restrict__ xh,
                                                  const f16* __restrict__ w1t,
                                                  const int* __restrict__ list,
                                                  const int* __restrict__ base,
                                                  f16* __restrict__ H, int cb, int nwg) {
  __shared__ __align__(16) char smem[32768 + 512];
  int* slist = (int*)(smem + 32768);
  int tid = threadIdx.x;
  int wk = xcd_swz(blockIdx.x, nwg);
  int bx = wk >> 4, by = wk & 15;
  int m0 = (cb + bx) * BM;
  int mloc = bx * BM;
  int h0 = by * BN1;
  int e = 0;
#pragma unroll
  for (int i = 1; i < 4; ++i) if (m0 >= base[i]) e = i;
  if (tid < BM) {
    int v = list[m0 + tid];
    slist[tid] = v < 0 ? 0 : v;
  }
  __syncthreads();

  int tokr[2];
#pragma unroll
  for (int i = 0; i < 2; ++i) tokr[i] = slist[i * 64 + (tid >> 2)];

  const f16* wB = w1t + (size_t)(e * FF + h0) * CDIM;
  int kbs = ((tid & 3) * 16) ^ (((tid >> 3) & 3) << 4);

  f32x4 acc[4][4] = {};
  int lane = tid & 63, w = tid >> 6, wr = w >> 1, wc = w & 1;

  auto stage = [&](int kk, int p) {
    char* s = smem + p * 16384;
#pragma unroll
    for (int i = 0; i < 2; ++i) {
      gload16(xh + (size_t)tokr[i] * CDIM + kk * BK + (kbs >> 1),
              s + i * 4096 + tid * 16);
    }
#pragma unroll
    for (int i = 0; i < 2; ++i) {
      int row = i * 64 + (tid >> 2);
      gload16(wB + (size_t)row * CDIM + kk * BK + (kbs >> 1),
              s + 8192 + i * 4096 + tid * 16);
    }
  };

  auto compute = [&](int p) {
    const char* s = smem + p * 16384;
    f16x8 af[4], bfr[4];
    int kb = (lane >> 4) * 16;
#pragma unroll
    for (int fr = 0; fr < 4; ++fr) {
      int row = wr * 64 + fr * 16 + (lane & 15);
      af[fr] = *(const f16x8*)(s + row * 64 + (kb ^ (((row >> 1) & 3) << 4)));
    }
#pragma unroll
    for (int fc = 0; fc < 4; ++fc) {
      int col = wc * 64 + fc * 16 + (lane & 15);
      bfr[fc] = *(const f16x8*)(s + 8192 + col * 64 + (kb ^ (((col >> 1) & 3) << 4)));
    }
#pragma unroll
    for (int fr = 0; fr < 4; ++fr)
#pragma unroll
      for (int fc = 0; fc < 4; ++fc)
        acc[fr][fc] = __builtin_amdgcn_mfma_f32_16x16x32_f16(af[fr], bfr[fc],
                                                             acc[fr][fc], 0, 0, 0);
  };

  stage(0, 0);
  __syncthreads();
  for (int kk = 0; kk < 16; ++kk) {
    if (kk < 15) stage(kk + 1, (kk + 1) & 1);
    __builtin_amdgcn_sched_barrier(0);
    __builtin_amdgcn_s_setprio(1);
    compute(kk & 1);
    __builtin_amdgcn_s_setprio(0);
    __syncthreads();
  }

#pragma unroll
  for (int fr = 0; fr < 4; ++fr)
#pragma unroll
    for (int fc = 0; fc < 4; ++fc)
#pragma unroll
      for (int i = 0; i < 4; ++i) {
        int row = wr * 64 + fr * 16 + (lane >> 4) * 4 + i;
        int col = wc * 64 + fc * 16 + (lane & 15);
        float v = gelu_fast(acc[fr][fc][i]);
        int off = (row * 256 + col * 2) ^ ((row & 7) << 4);
        *(f16*)(smem + off) = (f16)v;
      }
  __syncthreads();
#pragma unroll
  for (int j = 0; j < 8; ++j) {
    int row = j * 16 + (tid >> 4);
    int colb = ((tid & 15) * 16) ^ ((row & 7) << 4);
    uint4 v = *(const uint4*)(smem + row * 256 + colb);
    *(uint4*)((char*)H + ((size_t)(mloc + row) * FF + h0) * 2 + (tid & 15) * 16) = v;
  }
}

// ---------------- pass 2: Y[slot] = H[slot] @ W2e  (K = FF = 2048) ----------------
// R12 verbatim: 128x128, BK=32, dbuf 2x16KB, 4 blk/CU. Grid CB*4.

__global__ __launch_bounds__(256, 4) void k_gemm2(const f16* __restrict__ H,
                                                  const f16* __restrict__ w2t,
                                                  const int* __restrict__ base,
                                                  f16* __restrict__ Y, int cb, int nwg) {
  __shared__ __align__(16) char smem[32768];
  int tid = threadIdx.x;
  int wk = xcd_swz(blockIdx.x, nwg);
  int bx = wk >> 2, by = wk & 3;
  int m0 = (cb + bx) * BM;
  int mloc = bx * BM;
  int c0 = by * BN2;
  int e = 0;
#pragma unroll
  for (int i = 1; i < 4; ++i) if (m0 >= base[i]) e = i;

  const f16* pA = H + (size_t)mloc * FF;
  const f16* wB = w2t + (size_t)(e * CDIM + c0) * FF;
  int kbs = ((tid & 3) * 16) ^ (((tid >> 3) & 3) << 4);

  f32x4 acc[4][4] = {};
  int lane = tid & 63, w = tid >> 6, wr = w >> 1, wc = w & 1;

  auto stage = [&](int kk, int p) {
    char* s = smem + p * 16384;
#pragma unroll
    for (int i = 0; i < 2; ++i) {
      int row = i * 64 + (tid >> 2);
      gload16(pA + (size_t)row * FF + kk * BK + (kbs >> 1),
              s + i * 4096 + tid * 16);
    }
#pragma unroll
    for (int i = 0; i < 2; ++i) {
      int row = i * 64 + (tid >> 2);
      gload16(wB + (size_t)row * FF + kk * BK + (kbs >> 1),
              s + 8192 + i * 4096 + tid * 16);
    }
  };

  auto compute = [&](int p) {
    const char* s = smem + p * 16384;
    f16x8 af[4], bfr[4];
    int kb = (lane >> 4) * 16;
#pragma unroll
    for (int fr = 0; fr < 4; ++fr) {
      int row = wr * 64 + fr * 16 + (lane & 15);
      af[fr] = *(const f16x8*)(s + row * 64 + (kb ^ (((row >> 1) & 3) << 4)));
    }
#pragma unroll
    for (int fc = 0; fc < 4; ++fc) {
      int col = wc * 64 + fc * 16 + (lane & 15);
      bfr[fc] = *(const f16x8*)(s + 8192 + col * 64 + (kb ^ (((col >> 1) & 3) << 4)));
    }
#pragma unroll
    for (int fr = 0; fr < 4; ++fr)
#pragma unroll
      for (int fc = 0; fc < 4; ++fc)
        acc[fr][fc] = __builtin_amdgcn_mfma_f32_16x16x32_f16(af[fr], bfr[fc],
                                                             acc[fr][fc], 0, 0, 0);
  };

  stage(0, 0);
  __syncthreads();
  for (int kk = 0; kk < 64; ++kk) {
    if (kk < 63) stage(kk + 1, (kk + 1) & 1);
    __builtin_amdgcn_sched_barrier(0);
    __builtin_amdgcn_s_setprio(1);
    compute(kk & 1);
    __builtin_amdgcn_s_setprio(0);
    __syncthreads();
  }

#pragma unroll
  for (int fr = 0; fr < 4; ++fr)
#pragma unroll
    for (int fc = 0; fc < 4; ++fc)
#pragma unroll
      for (int i = 0; i < 4; ++i) {
        int row = wr * 64 + fr * 16 + (lane >> 4) * 4 + i;
        int col = wc * 64 + fc * 16 + (lane & 15);
        int off = (row * 256 + col * 2) ^ ((row & 7) << 4);
        *(f16*)(smem + off) = (f16)acc[fr][fc][i];
      }
  __syncthreads();
#pragma unroll
  for (int j = 0; j < 8; ++j) {
    int row = j * 16 + (tid >> 4);
    int colb = ((tid & 15) * 16) ^ ((row & 7) << 4);
    uint4 v = *(const uint4*)(smem + row * 256 + colb);
    *(uint4*)((char*)Y + ((size_t)(m0 + row) * CDIM + c0) * 2 + (tid & 15) * 16) = v;
  }
}

// ---------------- combine: out[tok] = w0*Y[s0] + w1*Y[s1] (16B loads) -------

__global__ __launch_bounds__(256) void k_combine(const f16* __restrict__ Y,
                                                 const float4* __restrict__ tokinfo,
                                                 const int2* __restrict__ tokslot,
                                                 float* __restrict__ out) {
  int gid = blockIdx.x * 256 + threadIdx.x;
  int tok = gid >> 6;
  int cc = (gid & 63) * 8;
  int2 sl = tokslot[tok];
  float4 ti = tokinfo[tok];
  f16x8 y0 = *(const f16x8*)(Y + (size_t)sl.x * CDIM + cc);
  f16x8 y1 = *(const f16x8*)(Y + (size_t)sl.y * CDIM + cc);
  float w0 = ti.z, w1 = ti.w;
  float4 o0, o1;
  o0.x = w0 * (float)y0[0] + w1 * (float)y1[0];
  o0.y = w0 * (float)y0[1] + w1 * (float)y1[1];
  o0.z = w0 * (float)y0[2] + w1 * (float)y1[2];
  o0.w = w0 * (float)y0[3] + w1 * (float)y1[3];
  o1.x = w0 * (float)y0[4] + w1 * (float)y1[4];
  o1.y = w0 * (float)y0[5] + w1 * (float)y1[5];
  o1.z = w0 * (float)y0[6] + w1 * (float)y1[6];
  o1.w = w0 * (float)y0[7] + w1 * (float)y1[7];
  float* orow = out + (size_t)tok * CDIM + cc;
  *(float4*)orow = o0;
  *(float4*)(orow + 4) = o1;
}

// ---------------- host ----------------

extern "C" void kernel_launch(void* const* d_in, const int* in_sizes, int n_in,
                              void* d_out, int out_size, void* d_ws, size_t ws_size,
                              hipStream_t stream) {
  const float* x  = (const float*)d_in[0];
  const float* gw = (const float*)d_in[1];
  const float* w1 = (const float*)d_in[2];
  const float* w2 = (const float*)d_in[3];
  float* out  = (float*)d_out;
  float* rout = out + (size_t)NTOK * CDIM;

  char* ws = (char*)d_ws;
  f16* xh      = (f16*)ws;      ws += (size_t)NTOK * CDIM * 2;       // 16.78 MB
  f16* w1t     = (f16*)ws;      ws += (size_t)NEXP * FF * CDIM * 2;  //  8.39 MB
  f16* w2t     = (f16*)ws;      ws += (size_t)NEXP * FF * CDIM * 2;  //  8.39 MB
  f16* Ybuf    = (f16*)ws;      ws += (size_t)CAP * CDIM * 2;        // 34.08 MB
  float4* tokinfo = (float4*)ws; ws += (size_t)NTOK * 16;            //  0.26 MB
  int2* tokslot = (int2*)ws;    ws += (size_t)NTOK * 8;              //  0.13 MB
  int* list    = (int*)ws;      ws += (size_t)CAP * 4;               //  0.13 MB
  int* bcnt    = (int*)ws;      ws += (size_t)RBLK * 4 * 4;          //  16 KB
  int* base    = (int*)ws;      ws += 64;
  int* cursor  = (int*)ws;      ws += 4 * CPAD * 4;
  f16* Hbuf    = (f16*)ws;      // CB*128*FF f16, sized by ladder below

  size_t base_bytes = (size_t)(ws - (char*)d_ws);
  const int opts[12] = {260, 130, 65, 52, 26, 20, 13, 10, 5, 4, 2, 1};
  int CB = 1;
  for (int oi = 0; oi < 12; ++oi) {
    if (base_bytes + (size_t)opts[oi] * BM * FF * 2 <= ws_size) { CB = opts[oi]; break; }
  }

  k_cast_t2<<<dim3(FF / 64, CDIM / 64, 8), 256, 0, stream>>>(w1, w1t, w2, w2t);
  k_router<<<RBLK, 256, 0, stream>>>(x, gw, xh, rout, tokinfo, bcnt);
  k_bases<<<1, 256, 0, stream>>>(bcnt, base, cursor, list);
  k_assign<<<NTOK / 1024, 256, 0, stream>>>(tokinfo, cursor, list, tokslot);

  for (int cb = 0; cb < NBLK; cb += CB) {
    int n1 = CB * 16, n2 = CB * 4;
    k_gemm1<<<n1, 256, 0, stream>>>(xh, w1t, list, base, Hbuf, cb, n1);
    k_gemm2<<<n2, 256, 0, stream>>>(Hbuf, w2t, base, Ybuf, cb, n2);
  }
  k_combine<<<NTOK * CDIM / 8 / 256, 256, 0, stream>>>(Ybuf, tokinfo, tokslot, out);
}